// Round 8
// baseline (468.599 us; speedup 1.0000x reference)
//
#include <hip/hip_runtime.h>
#include <hip/hip_bf16.h>

#define N_NODES 50000
#define N_EDGES 800000
#define DIN     128
#define HD      128   // H * D_HEAD
#define NHEAD   8
#define DHEAD   16

#define M_PAD        50176           // 1024 * 49
#define NREP         8               // histogram/cursor replicas
#define HIST_BLOCKS  3125            // 800000 / 256 exactly
#define CVTW_BLOCKS  192             // 3*128*128/256
#define PROJ_PM      391             // ceil(50000/128)

typedef __attribute__((ext_vector_type(8))) short short8;   // 8 bf16
typedef __attribute__((ext_vector_type(4))) float float4v;  // 4 fp32 acc

static __device__ __forceinline__ unsigned short f2bf_bits(float f) {
    __hip_bfloat16 b = __float2bfloat16(f);
    return *reinterpret_cast<unsigned short*>(&b);
}
static __device__ __forceinline__ float bfb(short b) {
    return __uint_as_float(((unsigned int)(unsigned short)b) << 16);
}
static __device__ __forceinline__ short8 cvt8(const float* p) {
    const float4 f0 = *(const float4*)p;
    const float4 f1 = *(const float4*)(p + 4);
    short8 r;
    r[0] = (short)f2bf_bits(f0.x); r[1] = (short)f2bf_bits(f0.y);
    r[2] = (short)f2bf_bits(f0.z); r[3] = (short)f2bf_bits(f0.w);
    r[4] = (short)f2bf_bits(f1.x); r[5] = (short)f2bf_bits(f1.y);
    r[6] = (short)f2bf_bits(f1.z); r[7] = (short)f2bf_bits(f1.w);
    return r;
}

// ---------------------------------------------------------------------------
// dst-histogram into 8 REPLICAS (replica = blockIdx&7) + W transpose/convert.
// Same-address atomic chains drop 16 -> 2 per (node, replica).
// ---------------------------------------------------------------------------
__global__ __launch_bounds__(256) void hist_cvtw_kernel(
    const int* __restrict__ dst,
    const float* __restrict__ Wq, const float* __restrict__ Wk,
    const float* __restrict__ Wv,
    int* __restrict__ cnt_pr, unsigned short* __restrict__ Wt)
{
    const int bid = blockIdx.x;
    if (bid < HIST_BLOCKS) {
        const int e = bid * 256 + threadIdx.x;       // grid sized exactly
        const int r = bid & (NREP - 1);
        atomicAdd(&cnt_pr[(size_t)dst[e] * NREP + r], 1);
    } else {
        const int i   = (bid - HIST_BLOCKS) * 256 + threadIdx.x; // < 49152
        const int n   = i & 127;
        const int k   = (i >> 7) & 127;
        const int mat = i >> 14;
        const float* W = (mat == 0) ? Wq : (mat == 1) ? Wk : Wv;
        Wt[mat * (DIN * HD) + n * DIN + k] = f2bf_bits(W[k * HD + n]);
    }
}

// ---------------------------------------------------------------------------
// Exclusive scan over cnt_pr[node][replica] (400k ints), ONE block.
// Thread t owns nodes [49t, 49t+49) = 392 CONTIGUOUS ints (two-pass to keep
// register use sane).  Writes: cursor_pr (scatter starts per (node,replica)),
// row_start[n] dense (aggregate), row_start[M_PAD] = total.
// ---------------------------------------------------------------------------
__global__ __launch_bounds__(1024) void scan_kernel(
    const int* __restrict__ cnt_pr, int* __restrict__ cursor_pr,
    int* __restrict__ row_start)
{
    __shared__ int s[1024];
    const int tid  = threadIdx.x;
    const int base = tid * 49 * NREP;            // first int owned

    // pass 1: sum my 392 contiguous ints
    int sum = 0;
    for (int i = 0; i < 49 * NREP; i += 4) {
        const int4 v = *(const int4*)(cnt_pr + base + i);
        sum += v.x + v.y + v.z + v.w;
    }

    s[tid] = sum;
    __syncthreads();
    for (int off = 1; off < 1024; off <<= 1) {
        int x = (tid >= off) ? s[tid - off] : 0;
        __syncthreads();
        s[tid] += x;
        __syncthreads();
    }
    int run = s[tid] - sum;                      // exclusive prefix

    // pass 2: re-read, emit cursors + dense row starts
    for (int n = 0; n < 49; ++n) {
        const int node = tid * 49 + n;
        row_start[node] = run;
        #pragma unroll
        for (int r = 0; r < NREP; ++r) {
            const int idx = node * NREP + r;
            cursor_pr[idx] = run;
            run += cnt_pr[idx];
        }
    }
    if (tid == 1023) row_start[M_PAD] = run;     // == N_EDGES
}

// ---------------------------------------------------------------------------
// Q/K/V projection via bf16 MFMA.  grid = (391, 3); blockIdx.y = matrix.
// A-fragments (h rows) converted fp32->bf16 in-register, Wt L1/L2-hot.
// ---------------------------------------------------------------------------
__global__ __launch_bounds__(256) void proj_kernel(
    const float* __restrict__ h,
    const unsigned short* __restrict__ Wt,
    const float* __restrict__ bq, const float* __restrict__ bk,
    const float* __restrict__ bv,
    float* __restrict__ Qf, __hip_bfloat16* __restrict__ KV)
{
    const int mat  = blockIdx.y;               // 0=Q, 1=K, 2=V
    const int wave = threadIdx.x >> 6;
    const int lane = threadIdx.x & 63;
    const int quad = lane >> 4;
    const int l16  = lane & 15;
    const int rowBase = blockIdx.x * 128 + wave * 32;

    int r0 = rowBase + l16;       if (r0 >= N_NODES) r0 = N_NODES - 1;
    int r1 = rowBase + 16 + l16;  if (r1 >= N_NODES) r1 = N_NODES - 1;

    short8 afr[2][4];
    #pragma unroll
    for (int kc = 0; kc < 4; ++kc) {
        const int ko = kc * 32 + quad * 8;
        afr[0][kc] = cvt8(h + (size_t)r0 * DIN + ko);
        afr[1][kc] = cvt8(h + (size_t)r1 * DIN + ko);
    }

    const unsigned short* wb = Wt + mat * (DIN * HD);
    const float* bias = (mat == 0) ? bq : (mat == 1) ? bk : bv;

    float4v acc[2][8];
    #pragma unroll
    for (int rt = 0; rt < 2; ++rt)
        #pragma unroll
        for (int ct = 0; ct < 8; ++ct)
            acc[rt][ct] = (float4v){0.f, 0.f, 0.f, 0.f};

    #pragma unroll
    for (int kc = 0; kc < 4; ++kc) {
        const int ko = kc * 32 + quad * 8;
        #pragma unroll
        for (int ct = 0; ct < 8; ++ct) {
            const short8 b = *(const short8*)(wb + (ct * 16 + l16) * DIN + ko);
            acc[0][ct] = __builtin_amdgcn_mfma_f32_16x16x32_bf16(afr[0][kc], b, acc[0][ct], 0, 0, 0);
            acc[1][ct] = __builtin_amdgcn_mfma_f32_16x16x32_bf16(afr[1][kc], b, acc[1][ct], 0, 0, 0);
        }
    }

    #pragma unroll
    for (int ct = 0; ct < 8; ++ct) {
        const int col = ct * 16 + l16;
        const float bcol = bias[col];
        #pragma unroll
        for (int rt = 0; rt < 2; ++rt) {
            #pragma unroll
            for (int r = 0; r < 4; ++r) {
                const int row = rowBase + rt * 16 + quad * 4 + r;
                if (row < N_NODES) {
                    const float v = acc[rt][ct][r] + bcol;
                    if (mat == 0)
                        Qf[(size_t)row * HD + col] = v;
                    else
                        KV[(size_t)row * 256 + (mat == 2 ? 128 : 0) + col] =
                            __float2bfloat16(v);
                }
            }
        }
    }
}

// ---------------------------------------------------------------------------
// Edge scatter using replicated cursors — MUST use the same edge->block->
// replica mapping as hist (same grid, r = blockIdx&7).
// ---------------------------------------------------------------------------
__global__ __launch_bounds__(256) void scatter_kernel(
    const int* __restrict__ src, const int* __restrict__ dst,
    int* __restrict__ cursor_pr, int* __restrict__ sorted_src)
{
    const int bid = blockIdx.x;
    const int e   = bid * 256 + threadIdx.x;     // grid sized exactly
    const int r   = bid & (NREP - 1);
    const int pos = atomicAdd(&cursor_pr[(size_t)dst[e] * NREP + r], 1);
    sorted_src[pos] = src[e];
}

// ---------------------------------------------------------------------------
// Aggregate.  One 128-thread block per destination node; edges in batches of
// 16.  Phase A: thread=(edge j, head h) computes the dot ONCE; Phase B:
// thread=(h,d) does the V-gather fma with LDS score broadcast.
// ---------------------------------------------------------------------------
__global__ __launch_bounds__(128) void aggregate_kernel(
    const float* __restrict__ Qf, const __hip_bfloat16* __restrict__ KV,
    const int* __restrict__ row_start, const int* __restrict__ sorted_src,
    float* __restrict__ out)
{
    const int node = blockIdx.x;
    const int t    = threadIdx.x;
    const int beg  = row_start[node];
    const int end  = row_start[node + 1];

    const int jA = t >> 3;     // edge slot in batch (0..15)
    const int hA = t & 7;      // head for phase A
    const int hB = t >> 4;     // head for phase B

    __shared__ float sc_s[16][8];
    __shared__ int   s_s[16];

    const float* qseg = Qf + (size_t)node * HD + hA * 16;
    const float4 q0 = *(const float4*)(qseg);
    const float4 q1 = *(const float4*)(qseg + 4);
    const float4 q2 = *(const float4*)(qseg + 8);
    const float4 q3 = *(const float4*)(qseg + 12);

    const short* kvb   = (const short*)KV;
    const short* vbase = kvb + 128 + t;

    float acc = 0.f, zacc = 0.f;

    for (int e0 = beg; e0 < end; e0 += 16) {
        const int nb = min(16, end - e0);

        if (jA < nb) {
            const int s = sorted_src[e0 + jA];
            if (hA == 0) s_s[jA] = s;
            const short* kp = kvb + (size_t)s * 256 + hA * 16;
            const short8 k0 = *(const short8*)kp;
            const short8 k1 = *(const short8*)(kp + 8);
            float dot;
            dot  = q0.x * bfb(k0[0]) + q0.y * bfb(k0[1])
                 + q0.z * bfb(k0[2]) + q0.w * bfb(k0[3]);
            dot += q1.x * bfb(k0[4]) + q1.y * bfb(k0[5])
                 + q1.z * bfb(k0[6]) + q1.w * bfb(k0[7]);
            dot += q2.x * bfb(k1[0]) + q2.y * bfb(k1[1])
                 + q2.z * bfb(k1[2]) + q2.w * bfb(k1[3]);
            dot += q3.x * bfb(k1[4]) + q3.y * bfb(k1[5])
                 + q3.z * bfb(k1[6]) + q3.w * bfb(k1[7]);
            sc_s[jA][hA] = __expf(fminf(fmaxf(dot * 0.25f, -5.f), 5.f));
        }
        __syncthreads();

        int j = 0;
        for (; j + 3 < nb; j += 4) {
            const int s0 = s_s[j],     s1 = s_s[j + 1];
            const int s2 = s_s[j + 2], s3 = s_s[j + 3];
            const float c0 = sc_s[j][hB],     c1 = sc_s[j + 1][hB];
            const float c2 = sc_s[j + 2][hB], c3 = sc_s[j + 3][hB];
            const float v0 = bfb(vbase[(size_t)s0 * 256]);
            const float v1 = bfb(vbase[(size_t)s1 * 256]);
            const float v2 = bfb(vbase[(size_t)s2 * 256]);
            const float v3 = bfb(vbase[(size_t)s3 * 256]);
            acc = fmaf(v0, c0, acc); acc = fmaf(v1, c1, acc);
            acc = fmaf(v2, c2, acc); acc = fmaf(v3, c3, acc);
            zacc += (c0 + c1) + (c2 + c3);
        }
        for (; j < nb; ++j) {
            const int s0 = s_s[j];
            const float c0 = sc_s[j][hB];
            acc = fmaf(bfb(vbase[(size_t)s0 * 256]), c0, acc);
            zacc += c0;
        }
        __syncthreads();
    }

    out[(size_t)node * HD + t] = acc / (zacc + 1e-6f);
}

// ---------------------------------------------------------------------------
extern "C" void kernel_launch(void* const* d_in, const int* in_sizes, int n_in,
                              void* d_out, int out_size, void* d_ws, size_t ws_size,
                              hipStream_t stream)
{
    const float* h   = (const float*)d_in[0];
    const float* Wq  = (const float*)d_in[1];
    const float* bq  = (const float*)d_in[2];
    const float* Wk  = (const float*)d_in[3];
    const float* bk  = (const float*)d_in[4];
    const float* Wv  = (const float*)d_in[5];
    const float* bv  = (const float*)d_in[6];
    const int*   src = (const int*)d_in[7];
    const int*   dst = (const int*)d_in[8];
    float* out = (float*)d_out;

    // workspace layout (16B-aligned segments):
    //   Qf fp32 [50000][128]             25.6 MB
    //   KV bf16 [50000][K128|V128]       25.6 MB
    //   Wt bf16 [3][128][128]             0.1 MB
    //   cnt_pr / cursor_pr int [M_PAD*8]  1.6 MB each
    //   row_start int [M_PAD+16]          0.2 MB
    //   sorted_src int [800000]           3.2 MB
    float* Qf = (float*)d_ws;
    __hip_bfloat16* KV = (__hip_bfloat16*)(Qf + (size_t)N_NODES * HD);
    unsigned short* Wt = (unsigned short*)(KV + (size_t)N_NODES * 256);
    int* cnt_pr     = (int*)(Wt + 3 * DIN * HD);
    int* cursor_pr  = cnt_pr + (size_t)M_PAD * NREP;
    int* row_start  = cursor_pr + (size_t)M_PAD * NREP;
    int* sorted_src = row_start + (M_PAD + 16);

    hipMemsetAsync(cnt_pr, 0, (size_t)M_PAD * NREP * sizeof(int), stream);

    hist_cvtw_kernel<<<HIST_BLOCKS + CVTW_BLOCKS, 256, 0, stream>>>(
        dst, Wq, Wk, Wv, cnt_pr, Wt);

    scan_kernel<<<1, 1024, 0, stream>>>(cnt_pr, cursor_pr, row_start);

    dim3 pgrid(PROJ_PM, 3);
    proj_kernel<<<pgrid, 256, 0, stream>>>(h, Wt, bq, bk, bv, Qf, KV);

    scatter_kernel<<<HIST_BLOCKS, 256, 0, stream>>>(
        src, dst, cursor_pr, sorted_src);

    aggregate_kernel<<<N_NODES, 128, 0, stream>>>(
        Qf, KV, row_start, sorted_src, out);
}

// Round 9
// 291.611 us; speedup vs baseline: 1.6069x; 1.6069x over previous
//
#include <hip/hip_runtime.h>
#include <hip/hip_bf16.h>

#define N_NODES 50000
#define N_EDGES 800000
#define DIN     128
#define HD      128   // H * D_HEAD
#define NHEAD   8
#define DHEAD   16

#define M_PAD        50176           // 1024 * 49
#define NREP         8               // histogram/cursor replicas
#define NSCAN        49              // scan blocks (1024 nodes each)
#define HIST_BLOCKS  3125            // 800000 / 256 exactly
#define CVTW_BLOCKS  192             // 3*128*128/256
#define PROJ_PM      391             // ceil(50000/128)

typedef __attribute__((ext_vector_type(8))) short short8;   // 8 bf16
typedef __attribute__((ext_vector_type(4))) float float4v;  // 4 fp32 acc

static __device__ __forceinline__ unsigned short f2bf_bits(float f) {
    __hip_bfloat16 b = __float2bfloat16(f);
    return *reinterpret_cast<unsigned short*>(&b);
}
static __device__ __forceinline__ float bfb(short b) {
    return __uint_as_float(((unsigned int)(unsigned short)b) << 16);
}
static __device__ __forceinline__ short8 cvt8(const float* p) {
    const float4 f0 = *(const float4*)p;
    const float4 f1 = *(const float4*)(p + 4);
    short8 r;
    r[0] = (short)f2bf_bits(f0.x); r[1] = (short)f2bf_bits(f0.y);
    r[2] = (short)f2bf_bits(f0.z); r[3] = (short)f2bf_bits(f0.w);
    r[4] = (short)f2bf_bits(f1.x); r[5] = (short)f2bf_bits(f1.y);
    r[6] = (short)f2bf_bits(f1.z); r[7] = (short)f2bf_bits(f1.w);
    return r;
}

// ---------------------------------------------------------------------------
// dst-histogram into 8 REPLICAS (replica = blockIdx&7) + W transpose/convert.
// ---------------------------------------------------------------------------
__global__ __launch_bounds__(256) void hist_cvtw_kernel(
    const int* __restrict__ dst,
    const float* __restrict__ Wq, const float* __restrict__ Wk,
    const float* __restrict__ Wv,
    int* __restrict__ cnt_pr, unsigned short* __restrict__ Wt)
{
    const int bid = blockIdx.x;
    if (bid < HIST_BLOCKS) {
        const int e = bid * 256 + threadIdx.x;       // grid sized exactly
        const int r = bid & (NREP - 1);
        atomicAdd(&cnt_pr[(size_t)dst[e] * NREP + r], 1);
    } else {
        const int i   = (bid - HIST_BLOCKS) * 256 + threadIdx.x; // < 49152
        const int n   = i & 127;
        const int k   = (i >> 7) & 127;
        const int mat = i >> 14;
        const float* W = (mat == 0) ? Wq : (mat == 1) ? Wk : Wv;
        Wt[mat * (DIN * HD) + n * DIN + k] = f2bf_bits(W[k * HD + n]);
    }
}

// ---------------------------------------------------------------------------
// Scan stage 1: per-block sums.  49 blocks x 256 thr; each thread reduces 32
// contiguous ints (block covers 8192 ints = 1024 nodes x 8 replicas).
// ---------------------------------------------------------------------------
__global__ __launch_bounds__(256) void scan_blocks_kernel(
    const int* __restrict__ cnt_pr, int* __restrict__ blockSums)
{
    __shared__ int s[256];
    const int tid  = threadIdx.x;
    const int base = blockIdx.x * 8192 + tid * 32;

    int sum = 0;
    #pragma unroll
    for (int i = 0; i < 32; i += 4) {
        const int4 v = *(const int4*)(cnt_pr + base + i);
        sum += v.x + v.y + v.z + v.w;
    }
    s[tid] = sum;
    __syncthreads();
    for (int off = 128; off > 0; off >>= 1) {
        if (tid < off) s[tid] += s[tid + off];
        __syncthreads();
    }
    if (tid == 0) blockSums[blockIdx.x] = s[0];
}

// ---------------------------------------------------------------------------
// Scan stage 2: recompute block-local scan + add global base; write padded
// cursors and dense row starts.  49 blocks x 256 thr, thread owns 32 ints
// (= 4 nodes x 8 replicas).
// ---------------------------------------------------------------------------
__global__ __launch_bounds__(256) void add_write_kernel(
    const int* __restrict__ cnt_pr, const int* __restrict__ blockSums,
    int* __restrict__ cursor_pr, int* __restrict__ row_start)
{
    __shared__ int s[256];
    __shared__ int bs[NSCAN];
    const int tid  = threadIdx.x;
    const int bid  = blockIdx.x;
    const int base = bid * 8192 + tid * 32;

    if (tid < NSCAN) bs[tid] = blockSums[tid];

    int c[32];
    int sum = 0;
    #pragma unroll
    for (int i = 0; i < 32; i += 4) {
        const int4 v = *(const int4*)(cnt_pr + base + i);
        c[i] = v.x; c[i + 1] = v.y; c[i + 2] = v.z; c[i + 3] = v.w;
        sum += v.x + v.y + v.z + v.w;
    }
    s[tid] = sum;
    __syncthreads();
    for (int off = 1; off < 256; off <<= 1) {
        int x = (tid >= off) ? s[tid - off] : 0;
        __syncthreads();
        s[tid] += x;
        __syncthreads();
    }

    int gbase = 0;
    for (int i = 0; i < bid; ++i) gbase += bs[i];   // <=48 LDS reads

    int run = gbase + s[tid] - sum;
    const int node0 = bid * 1024 + tid * 4;
    #pragma unroll
    for (int i = 0; i < 32; ++i) {
        if ((i & 7) == 0) row_start[node0 + (i >> 3)] = run;
        cursor_pr[base + i] = run;
        run += c[i];
    }
    if (bid == NSCAN - 1 && tid == 255) row_start[M_PAD] = run;
}

// ---------------------------------------------------------------------------
// Q/K/V projection via bf16 MFMA.  grid = (391, 3); blockIdx.y = matrix.
// ---------------------------------------------------------------------------
__global__ __launch_bounds__(256) void proj_kernel(
    const float* __restrict__ h,
    const unsigned short* __restrict__ Wt,
    const float* __restrict__ bq, const float* __restrict__ bk,
    const float* __restrict__ bv,
    float* __restrict__ Qf, __hip_bfloat16* __restrict__ KV)
{
    const int mat  = blockIdx.y;               // 0=Q, 1=K, 2=V
    const int wave = threadIdx.x >> 6;
    const int lane = threadIdx.x & 63;
    const int quad = lane >> 4;
    const int l16  = lane & 15;
    const int rowBase = blockIdx.x * 128 + wave * 32;

    int r0 = rowBase + l16;       if (r0 >= N_NODES) r0 = N_NODES - 1;
    int r1 = rowBase + 16 + l16;  if (r1 >= N_NODES) r1 = N_NODES - 1;

    short8 afr[2][4];
    #pragma unroll
    for (int kc = 0; kc < 4; ++kc) {
        const int ko = kc * 32 + quad * 8;
        afr[0][kc] = cvt8(h + (size_t)r0 * DIN + ko);
        afr[1][kc] = cvt8(h + (size_t)r1 * DIN + ko);
    }

    const unsigned short* wb = Wt + mat * (DIN * HD);
    const float* bias = (mat == 0) ? bq : (mat == 1) ? bk : bv;

    float4v acc[2][8];
    #pragma unroll
    for (int rt = 0; rt < 2; ++rt)
        #pragma unroll
        for (int ct = 0; ct < 8; ++ct)
            acc[rt][ct] = (float4v){0.f, 0.f, 0.f, 0.f};

    #pragma unroll
    for (int kc = 0; kc < 4; ++kc) {
        const int ko = kc * 32 + quad * 8;
        #pragma unroll
        for (int ct = 0; ct < 8; ++ct) {
            const short8 b = *(const short8*)(wb + (ct * 16 + l16) * DIN + ko);
            acc[0][ct] = __builtin_amdgcn_mfma_f32_16x16x32_bf16(afr[0][kc], b, acc[0][ct], 0, 0, 0);
            acc[1][ct] = __builtin_amdgcn_mfma_f32_16x16x32_bf16(afr[1][kc], b, acc[1][ct], 0, 0, 0);
        }
    }

    #pragma unroll
    for (int ct = 0; ct < 8; ++ct) {
        const int col = ct * 16 + l16;
        const float bcol = bias[col];
        #pragma unroll
        for (int rt = 0; rt < 2; ++rt) {
            #pragma unroll
            for (int r = 0; r < 4; ++r) {
                const int row = rowBase + rt * 16 + quad * 4 + r;
                if (row < N_NODES) {
                    const float v = acc[rt][ct][r] + bcol;
                    if (mat == 0)
                        Qf[(size_t)row * HD + col] = v;
                    else
                        KV[(size_t)row * 256 + (mat == 2 ? 128 : 0) + col] =
                            __float2bfloat16(v);
                }
            }
        }
    }
}

// ---------------------------------------------------------------------------
// Edge scatter using replicated cursors (same edge->replica map as hist).
// ---------------------------------------------------------------------------
__global__ __launch_bounds__(256) void scatter_kernel(
    const int* __restrict__ src, const int* __restrict__ dst,
    int* __restrict__ cursor_pr, int* __restrict__ sorted_src)
{
    const int bid = blockIdx.x;
    const int e   = bid * 256 + threadIdx.x;     // grid sized exactly
    const int r   = bid & (NREP - 1);
    const int pos = atomicAdd(&cursor_pr[(size_t)dst[e] * NREP + r], 1);
    sorted_src[pos] = src[e];
}

// ---------------------------------------------------------------------------
// Aggregate: one 128-thread block per node, 16-edge batches, two phases.
// ---------------------------------------------------------------------------
__global__ __launch_bounds__(128) void aggregate_kernel(
    const float* __restrict__ Qf, const __hip_bfloat16* __restrict__ KV,
    const int* __restrict__ row_start, const int* __restrict__ sorted_src,
    float* __restrict__ out)
{
    const int node = blockIdx.x;
    const int t    = threadIdx.x;
    const int beg  = row_start[node];
    const int end  = row_start[node + 1];

    const int jA = t >> 3;     // edge slot in batch (0..15)
    const int hA = t & 7;      // head for phase A
    const int hB = t >> 4;     // head for phase B

    __shared__ float sc_s[16][8];
    __shared__ int   s_s[16];

    const float* qseg = Qf + (size_t)node * HD + hA * 16;
    const float4 q0 = *(const float4*)(qseg);
    const float4 q1 = *(const float4*)(qseg + 4);
    const float4 q2 = *(const float4*)(qseg + 8);
    const float4 q3 = *(const float4*)(qseg + 12);

    const short* kvb   = (const short*)KV;
    const short* vbase = kvb + 128 + t;

    float acc = 0.f, zacc = 0.f;

    for (int e0 = beg; e0 < end; e0 += 16) {
        const int nb = min(16, end - e0);

        if (jA < nb) {
            const int s = sorted_src[e0 + jA];
            if (hA == 0) s_s[jA] = s;
            const short* kp = kvb + (size_t)s * 256 + hA * 16;
            const short8 k0 = *(const short8*)kp;
            const short8 k1 = *(const short8*)(kp + 8);
            float dot;
            dot  = q0.x * bfb(k0[0]) + q0.y * bfb(k0[1])
                 + q0.z * bfb(k0[2]) + q0.w * bfb(k0[3]);
            dot += q1.x * bfb(k0[4]) + q1.y * bfb(k0[5])
                 + q1.z * bfb(k0[6]) + q1.w * bfb(k0[7]);
            dot += q2.x * bfb(k1[0]) + q2.y * bfb(k1[1])
                 + q2.z * bfb(k1[2]) + q2.w * bfb(k1[3]);
            dot += q3.x * bfb(k1[4]) + q3.y * bfb(k1[5])
                 + q3.z * bfb(k1[6]) + q3.w * bfb(k1[7]);
            sc_s[jA][hA] = __expf(fminf(fmaxf(dot * 0.25f, -5.f), 5.f));
        }
        __syncthreads();

        int j = 0;
        for (; j + 3 < nb; j += 4) {
            const int s0 = s_s[j],     s1 = s_s[j + 1];
            const int s2 = s_s[j + 2], s3 = s_s[j + 3];
            const float c0 = sc_s[j][hB],     c1 = sc_s[j + 1][hB];
            const float c2 = sc_s[j + 2][hB], c3 = sc_s[j + 3][hB];
            const float v0 = bfb(vbase[(size_t)s0 * 256]);
            const float v1 = bfb(vbase[(size_t)s1 * 256]);
            const float v2 = bfb(vbase[(size_t)s2 * 256]);
            const float v3 = bfb(vbase[(size_t)s3 * 256]);
            acc = fmaf(v0, c0, acc); acc = fmaf(v1, c1, acc);
            acc = fmaf(v2, c2, acc); acc = fmaf(v3, c3, acc);
            zacc += (c0 + c1) + (c2 + c3);
        }
        for (; j < nb; ++j) {
            const int s0 = s_s[j];
            const float c0 = sc_s[j][hB];
            acc = fmaf(bfb(vbase[(size_t)s0 * 256]), c0, acc);
            zacc += c0;
        }
        __syncthreads();
    }

    out[(size_t)node * HD + t] = acc / (zacc + 1e-6f);
}

// ---------------------------------------------------------------------------
extern "C" void kernel_launch(void* const* d_in, const int* in_sizes, int n_in,
                              void* d_out, int out_size, void* d_ws, size_t ws_size,
                              hipStream_t stream)
{
    const float* h   = (const float*)d_in[0];
    const float* Wq  = (const float*)d_in[1];
    const float* bq  = (const float*)d_in[2];
    const float* Wk  = (const float*)d_in[3];
    const float* bk  = (const float*)d_in[4];
    const float* Wv  = (const float*)d_in[5];
    const float* bv  = (const float*)d_in[6];
    const int*   src = (const int*)d_in[7];
    const int*   dst = (const int*)d_in[8];
    float* out = (float*)d_out;

    float* Qf = (float*)d_ws;
    __hip_bfloat16* KV = (__hip_bfloat16*)(Qf + (size_t)N_NODES * HD);
    unsigned short* Wt = (unsigned short*)(KV + (size_t)N_NODES * 256);
    int* cnt_pr     = (int*)(Wt + 3 * DIN * HD);
    int* cursor_pr  = cnt_pr + (size_t)M_PAD * NREP;
    int* row_start  = cursor_pr + (size_t)M_PAD * NREP;
    int* blockSums  = row_start + (M_PAD + 16);
    int* sorted_src = blockSums + 64;

    hipMemsetAsync(cnt_pr, 0, (size_t)M_PAD * NREP * sizeof(int), stream);

    hist_cvtw_kernel<<<HIST_BLOCKS + CVTW_BLOCKS, 256, 0, stream>>>(
        dst, Wq, Wk, Wv, cnt_pr, Wt);

    scan_blocks_kernel<<<NSCAN, 256, 0, stream>>>(cnt_pr, blockSums);
    add_write_kernel<<<NSCAN, 256, 0, stream>>>(
        cnt_pr, blockSums, cursor_pr, row_start);

    dim3 pgrid(PROJ_PM, 3);
    proj_kernel<<<pgrid, 256, 0, stream>>>(h, Wt, bq, bk, bv, Qf, KV);

    scatter_kernel<<<HIST_BLOCKS, 256, 0, stream>>>(
        src, dst, cursor_pr, sorted_src);

    aggregate_kernel<<<N_NODES, 128, 0, stream>>>(
        Qf, KV, row_start, sorted_src, out);
}